// Round 1
// 100.088 us; speedup vs baseline: 1.0012x; 1.0012x over previous
//
#include <hip/hip_runtime.h>
#include <math.h>

// VoltageNet, round 13: R12 + (a) nodes[] slot permutation, (b) shfl-tree
// block combines for Tsum / lo-hi.
//   R12 post-mortem: metric is ~80% harness poison fills (2x 256MiB @ ~42us,
//   80% HBM peak — their roofline). Kernel ~20us vs 10.7us HBM floor.
//   Remaining controllable DS terms:
//   (a) P2b LUT reads nodes[k]: k follows the SOC random walk — adjacent
//       lanes differ by dk ~ +-7-8 nodes, wave spread ~60. Linear layout has
//       bank class = k mod 8, so dk=8 (the typical lane step!) fully
//       collides. sigma(k) = k ^ (k>>3) is a bijection that XORs HIGH bits
//       into the class bits: dk in {8..56} all change class (first collision
//       dk=64). Write side (consecutive tid) stays balanced. NOTE: an odd
//       multiplicative perm does NOT work (preserves dk%8==0 collisions).
//   (b) Tsum (8 broadcast reads/thread) and lo/hi (24 reads/thread) combine
//       loops -> lanes<NW read one aggregate + shfl trees (3 reads + ~14
//       shfl). woff/AoBo serial loops kept (avg 3.5 iters, wash). Rounding
//       deltas are ulp-level and only touch Tmean / the padded LUT range.
//   Exact k computation, scans, affine math unchanged from verified R12.
//   PERMANENT LESSONS: per-thread-chunk nt stores = HBM RMW (R9); per-thread
//   chunk LOADS thrash L1 under 16-wave interleave (R6: FETCH 37 vs 24.7MB);
//   launch_bounds must not cap VGPR below working set (R5); pad-4 layout is
//   balanced (8 dwords/bank) for P1 writes AND P2a b128 reads — verified by
//   quad-class arithmetic, do not "fix" it.
//   KEY INSIGHT (R5): per block, (R0,Tmean) const -> soc -> (OCV,R1,C) is 1-D;
//   256-node nearest LUT with EXACT reference math at nodes.
//   UH == 0 identically (theta[3]=theta[4]=0 since LB==UB==0) -> 1-state affine
//   recurrence, parallelized as an affine-map scan.

#define TT    8192
#define BLK   512
#define NW    8
#define EPT   16
#define NNODE 256
#define PADJ(j) ((j) + 4 * ((j) >> 5))
#define LDSN  (TT + 4 * (TT / 32) + 4)
#define NPERM(k) ((k) ^ ((k) >> 3))

typedef float vfloat4 __attribute__((ext_vector_type(4)));

__device__ __forceinline__ float frcp(float x) { return __builtin_amdgcn_rcpf(x); }
__device__ __forceinline__ float fsig(float x) { return frcp(1.0f + __expf(-x)); }
__device__ __forceinline__ float ftanh_x(float x) {
    return 1.0f - 2.0f * frcp(__expf(2.0f * x) + 1.0f);
}
__device__ __forceinline__ float fsoftplus_x(float z) {
    return fmaxf(z, 0.0f) + __logf(1.0f + __expf(-fabsf(z)));
}

// Exact reference chain at one soc value (per-block constants folded in pre1).
__device__ __forceinline__ void eval_chain(float soc,
    const float* __restrict__ w1, const float* __restrict__ pre1,
    const float* __restrict__ w2, const float* __restrict__ bb2,
    float& OCV, float& R1, float& C, float& OCVU)
{
    float h[6];
    #pragma unroll
    for (int i = 0; i < 6; ++i)
        h[i] = fsoftplus_x(fmaf(soc, w1[i], pre1[i]));
    float p0 = bb2[0], p1 = bb2[1], p2 = bb2[2], p5 = bb2[5], p6 = bb2[6];
    #pragma unroll
    for (int i = 0; i < 6; ++i) {
        p0 = fmaf(h[i], w2[7*i + 0], p0);
        p1 = fmaf(h[i], w2[7*i + 1], p1);
        p2 = fmaf(h[i], w2[7*i + 2], p2);
        p5 = fmaf(h[i], w2[7*i + 5], p5);
        p6 = fmaf(h[i], w2[7*i + 6], p6);
    }
    R1   = 0.04f * fsig(0.01f * p0);
    C    = 1e-6f * fsig(0.01f * p1);
    OCVU = fmaf(0.75f,    fsig(0.01f * p2), 0.05f);
    float ox = fmaf(0.79764f, fsig(0.01f * p5), 0.04236f);
    float oy = fmaf(0.82504f, fsig(0.01f * p6), 0.023f);
    float up = fmaf(oy, fmaf(oy, fmaf(oy, fmaf(oy, fmaf(oy, -2.2166f, 3.5146f),
                    -2.0843f), 1.6225f), -1.6518f), 4.4167f);
    up -= 4.0f * __expf(fmaf(109.451f, oy, -100.006f));
    float un = 0.063f + 0.8f * __expf(-75.0f * (ox + 0.001f));
    un = fmaf(-0.012f,  ftanh_x((ox - 0.127f) * 62.5f),        un);
    un = fmaf(-0.0118f, ftanh_x((ox - 0.155f) * 62.5f),        un);
    un = fmaf(-0.0035f, ftanh_x((ox - 0.22f)  * 50.0f),        un);
    un = fmaf(-0.0095f, ftanh_x((ox - 0.19f)  * 76.9230769f),  un);
    un = fmaf(-0.0145f, ftanh_x((ox - 0.49f)  * 50.0f),        un);
    un = fmaf(-0.08f,   ftanh_x((ox - 1.03f)  * 18.1818182f),  un);
    OCV = up - un;
}

__global__ void __launch_bounds__(BLK, 4)
voltnet_kernel(const float* __restrict__ X, const float* __restrict__ SC,
               const float* __restrict__ W1, const float* __restrict__ b1,
               const float* __restrict__ W2, const float* __restrict__ b2,
               float* __restrict__ out)
{
    __shared__ __align__(16) float ldsT[LDSN];   // t -> (later) output staging
    __shared__ __align__(16) float ldsI[LDSN];   // I
    __shared__ float  tw[NW], dw[NW], mnw[NW], mxw[NW], sA[NW], sB[NW];
    __shared__ float4 nodes[NNODE];
    __shared__ float  bcU10;

    const int b    = blockIdx.x;
    const int tid  = threadIdx.x;
    const int lane = tid & 63;
    const int wv   = tid >> 6;
    const int s    = tid * EPT;
    const int ps   = PADJ(s);          // padded start of this thread's 16 elems

    const float* __restrict__ Xrow = X + (size_t)b * TT * 3;
    const float Q  = SC[2 * b + 0];
    const float R0 = SC[2 * b + 1];

    // weights -> uniform (SGPR) loads
    float w1[18], bb1[6], w2[42], bb2[7];
    #pragma unroll
    for (int i = 0; i < 18; ++i) w1[i] = W1[i];
    #pragma unroll
    for (int i = 0; i < 6;  ++i) bb1[i] = b1[i];
    #pragma unroll
    for (int i = 0; i < 42; ++i) w2[i] = W2[i];
    #pragma unroll
    for (int i = 0; i < 7;  ++i) bb2[i] = b2[i];

    // ---- Phase 1: float4-triple loads, pack groups, b128 LDS writes ----
    //   group p owns elements j0=4p..4p+3 (never straddles a pad block):
    //   q0={t0,I0,T0,t1} q1={I1,T1,t2,I2} q2={T2,t3,I3,T3}
    const float4* __restrict__ Xq = (const float4*)Xrow;
    float tsum = 0.0f;
    #pragma unroll
    for (int it = 0; it < 4; ++it) {
        int p  = tid + it * BLK;
        float4 q0 = Xq[3 * p + 0];
        float4 q1 = Xq[3 * p + 1];
        float4 q2 = Xq[3 * p + 2];
        int jp = PADJ(4 * p);                     // mult of 4 -> 16B aligned
        vfloat4 tq = { q0.x, q0.w, q1.z, q2.y };
        vfloat4 iq = { q0.y, q1.x, q1.w, q2.z };
        *(__shared__ vfloat4*)&ldsT[jp] = tq;
        *(__shared__ vfloat4*)&ldsI[jp] = iq;
        tsum += (q0.z + q1.y) + (q2.x + q2.w);
    }
    #pragma unroll
    for (int d = 32; d > 0; d >>= 1) tsum += __shfl_down(tsum, d, 64);
    if (lane == 0) tw[wv] = tsum;
    __syncthreads();                                    // S1

    // Tmean combine: lanes<NW read one aggregate, shfl tree (was 8 reads/thr)
    float tv = (lane < NW) ? tw[lane] : 0.0f;
    #pragma unroll
    for (int d = 1; d < NW; d <<= 1) tv += __shfl_xor(tv, d, 64);
    const float Tmean = __shfl(tv, 0, 64) * (1.0f / (float)TT);

    float pre1[6];
    #pragma unroll
    for (int o = 0; o < 6; ++o)
        pre1[o] = fmaf(R0, w1[6 + o], fmaf(Tmean, w1[12 + o], bb1[o]));

    // ---- Phase 2a: b128 reads into registers; local SOC prefix ----
    float tprev = 0.0f, iprev = 0.0f;
    if (tid > 0) { tprev = ldsT[PADJ(s - 1)]; iprev = ldsI[PADJ(s - 1)]; }
    const float inext_last = (tid < BLK - 1) ? ldsI[PADJ(s + EPT)] : 0.0f;

    vfloat4 tq4[4], iq4[4];
    #pragma unroll
    for (int c = 0; c < 4; ++c) {
        tq4[c] = *(const __shared__ vfloat4*)&ldsT[ps + 4 * c];
        iq4[c] = *(const __shared__ vfloat4*)&ldsI[ps + 4 * c];
    }

    float lp[EPT], Ireg[EPT];
    float run = 0.0f;
    float mnl = 1e30f, mxl = -1e30f;
    #pragma unroll
    for (int e = 0; e < EPT; ++e) {
        float tt = tq4[e >> 2][e & 3];
        float ii = iq4[e >> 2][e & 3];
        float ds = (ii + iprev) * (tt - tprev) * (1.0f / 36000.0f);
        if (s + e == 0) ds = 0.0f;
        run += ds;
        lp[e]   = run;          // inclusive local prefix (registers)
        Ireg[e] = ii;
        mnl = fminf(mnl, run);
        mxl = fmaxf(mxl, run);
        tprev = tt; iprev = ii;
    }
    float inc = run;
    #pragma unroll
    for (int d = 1; d < 64; d <<= 1) {
        float v = __shfl_up(inc, d, 64);
        if (lane >= d) inc += v;
    }
    // wave min/max of local prefix (relative to wave start)
    float mn_t = (inc - run) + mnl, mx_t = (inc - run) + mxl;
    #pragma unroll
    for (int d = 32; d > 0; d >>= 1) {
        mn_t = fminf(mn_t, __shfl_down(mn_t, d, 64));
        mx_t = fmaxf(mx_t, __shfl_down(mx_t, d, 64));
    }
    if (lane == 63) dw[wv] = inc;
    if (lane == 0) { mnw[wv] = mn_t; mxw[wv] = mx_t; }
    __syncthreads();                                    // S2

    float woff = 0.0f;
    for (int w = 0; w < wv; ++w) woff += dw[w];         // wave-uniform
    const float soc_base = fmaf(Q, 0.2f, woff + (inc - run));

    // block lo/hi of soc: lanes<NW hold one wave aggregate, shfl scan+reduce
    // (was 24 broadcast LDS reads/thread). Rounding delta vs serial loop is
    // ulp-level, absorbed by the range pad below.
    float lo, hi;
    {
        float dv  = (lane < NW) ? dw[lane]  : 0.0f;
        float mnv = (lane < NW) ? mnw[lane] : 1e30f;
        float mxv = (lane < NW) ? mxw[lane] : -1e30f;
        float pv = dv;
        #pragma unroll
        for (int d = 1; d < NW; d <<= 1) {
            float u = __shfl_up(pv, d, 64);
            if (lane >= d) pv += u;
        }
        float ex = pv - dv;                 // exclusive prefix at this lane
        float cl = ex + mnv, ch = ex + mxv;
        #pragma unroll
        for (int d = 1; d < NW; d <<= 1) {
            cl = fminf(cl, __shfl_xor(cl, d, 64));
            ch = fmaxf(ch, __shfl_xor(ch, d, 64));
        }
        lo = fmaf(Q, 0.2f, __shfl(cl, 0, 64));
        hi = fmaf(Q, 0.2f, __shfl(ch, 0, 64));
        float pad = fmaf(hi - lo, 1.0f / 256.0f, 1e-7f);
        lo -= pad; hi += pad;
    }
    const float hstep = (hi - lo) * (1.0f / (float)(NNODE - 1));
    const float invh  = (float)(NNODE - 1) * frcp(hi - lo);

    // ---- Node evaluation: exact reference chain at 256 soc nodes ----
    //   Stored at permuted slot NPERM(k): soc walk makes lane-to-lane dk~+-8,
    //   which collides mod-8 bank classes in a linear layout.
    if (tid < NNODE) {
        float OCV, R1v, Cv, OCVU;
        eval_chain(fmaf((float)tid, hstep, lo), w1, pre1, w2, bb2, OCV, R1v, Cv, OCVU);
        nodes[NPERM(tid)] = make_float4(OCV, R1v, Cv, 0.0f);
    }
    if (tid == 0) {
        float OCV, R1v, Cv, OCVU;
        eval_chain(Q * 0.2f, w1, pre1, w2, bb2, OCV, R1v, Cv, OCVU);  // soc(j=0)=Q/5
        bcU10 = -OCVU - Ireg[0] * R0;
    }
    __syncthreads();                                    // S3

    // ---- Phase 2b: nearest-node LUT + affine coeffs; stash P->lp, Apre->Ireg ----
    float Ap = 1.0f, Bp = 0.0f;
    #pragma unroll 4
    for (int e = 0; e < EPT; ++e) {
        float soc = soc_base + lp[e];
        float ii  = Ireg[e];
        float inx = (e == EPT - 1) ? inext_last : Ireg[e + 1];

        int k = (int)fmaf(soc - lo, invh, 0.5f);
        k = (k < 0) ? 0 : ((k > NNODE - 1) ? NNODE - 1 : k);
        float4 n = nodes[NPERM(k)];

        // stash: pred[j] = P + Apre * U1_at_thread_start   (UH == 0)
        lp[e]   = fmaf(ii, R0, n.x) + Bp;
        Ireg[e] = Ap;

        float g  = (inx - ii) * n.z;
        float aj = 1.0f - g;
        float bj = g * n.y * ii;
        if (s + e == TT - 1) { aj = 1.0f; bj = 0.0f; }
        Bp = fmaf(aj, Bp, bj);
        Ap = aj * Ap;
    }

    // ---- affine block scan ((a2,b2)o(a1,b1) = (a2*a1, a2*b1+b2)) ----
    float A = Ap, B = Bp;
    #pragma unroll
    for (int d = 1; d < 64; d <<= 1) {
        float Au = __shfl_up(A, d, 64);
        float Bu = __shfl_up(B, d, 64);
        if (lane >= d) { B = fmaf(A, Bu, B); A = A * Au; }
    }
    float Aex = __shfl_up(A, 1, 64);
    float Bex = __shfl_up(B, 1, 64);
    if (lane == 0) { Aex = 1.0f; Bex = 0.0f; }
    if (lane == 63) { sA[wv] = A; sB[wv] = B; }
    __syncthreads();                                    // S4
    float Ao = 1.0f, Bo = 0.0f;
    for (int w = 0; w < wv; ++w) {                      // wave-uniform
        Bo = fmaf(sA[w], Bo, sB[w]);
        Ao = sA[w] * Ao;
    }
    const float U1s = fmaf(Aex * Ao, bcU10, fmaf(Aex, Bo, Bex));

    // ---- Phase 3: combine in regs, b128 staging, coalesced scalar nt stores ----
    #pragma unroll
    for (int c = 0; c < 4; ++c) {
        vfloat4 o;
        o.x = fmaf(Ireg[4 * c + 0], U1s, lp[4 * c + 0]);
        o.y = fmaf(Ireg[4 * c + 1], U1s, lp[4 * c + 1]);
        o.z = fmaf(Ireg[4 * c + 2], U1s, lp[4 * c + 2]);
        o.w = fmaf(Ireg[4 * c + 3], U1s, lp[4 * c + 3]);
        *(__shared__ vfloat4*)&ldsT[ps + 4 * c] = o;
    }
    __syncthreads();                                    // S5
    float* __restrict__ orow = out + (size_t)b * TT;
    #pragma unroll 4
    for (int it = 0; it < EPT; ++it) {
        int j = tid + it * BLK;
        __builtin_nontemporal_store(ldsT[PADJ(j)], &orow[j]);  // full 64B lines
    }
}

extern "C" void kernel_launch(void* const* d_in, const int* in_sizes, int n_in,
                              void* d_out, int out_size, void* d_ws, size_t ws_size,
                              hipStream_t stream)
{
    const float* X  = (const float*)d_in[0];
    const float* SC = (const float*)d_in[1];
    const float* W1 = (const float*)d_in[2];
    const float* b1 = (const float*)d_in[3];
    const float* W2 = (const float*)d_in[4];
    const float* b2 = (const float*)d_in[5];
    float* outp = (float*)d_out;
    const int B = in_sizes[1] / 2;   // SC is (B,2)
    hipLaunchKernelGGL(voltnet_kernel, dim3(B), dim3(BLK), 0, stream,
                       X, SC, W1, b1, W2, b2, outp);
}

// Round 2
// 99.850 us; speedup vs baseline: 1.0036x; 1.0024x over previous
//
#include <hip/hip_runtime.h>
#include <math.h>

// VoltageNet, round 14: wave-autonomous front/back ends, 5 barriers -> 3.
//   R13 post-mortem: nodes-perm + shfl combines = NEUTRAL (-0.12us, noise).
//   Lesson: DS micro-costs are hidden under memory waits at 16 waves/CU —
//   only critical-path structure matters now. Metric = ~84us harness fills
//   (80% HBM peak, their roofline) + ~16-20us kernel vs 10.7us HBM floor.
//   R14 structure: each wave stages/transposes/prefixes ITS OWN 1024-elem
//   region (wave-local LDS producer->consumer needs only lgkmcnt(0), no
//   barrier), so front-end VALU/DS overlaps the BW-bound load window instead
//   of serializing behind a block-wide S1. Lane-0 cross-wave (tprev,iprev)
//   comes from one redundant 16B global load (L2 hit). Back end: store loop
//   made wave-local (j = 1024*wv + 64*c + lane, still full 64B lines) -> S5
//   deleted; store tail skews across waves. Remaining barriers are the 3
//   algorithmically-required block exchanges: aggregates (Tmean/dw/min/max),
//   node table, affine aggregates.
//   PERMANENT LESSONS: per-thread-chunk nt stores = HBM RMW (R9); per-thread
//   chunk LOADS thrash L1 under 16-wave interleave (R6: FETCH 37 vs 24.7MB);
//   launch_bounds must not cap VGPR below working set (R5); pad-4 layout is
//   balanced for P1 writes AND P2a b128 reads; DS bank tuning is off the
//   critical path (R13) — do not re-mine it.
//   KEY INSIGHT (R5): per block, (R0,Tmean) const -> soc -> (OCV,R1,C) is 1-D;
//   256-node nearest LUT with EXACT reference math at nodes.
//   UH == 0 identically (theta[3]=theta[4]=0 since LB==UB==0) -> 1-state affine
//   recurrence, parallelized as an affine-map scan.

#define TT    8192
#define BLK   512
#define NW    8
#define EPT   16
#define NNODE 256
#define PADJ(j) ((j) + 4 * ((j) >> 5))
#define LDSN  (TT + 4 * (TT / 32) + 4)
#define NPERM(k) ((k) ^ ((k) >> 3))

typedef float vfloat4 __attribute__((ext_vector_type(4)));

__device__ __forceinline__ float frcp(float x) { return __builtin_amdgcn_rcpf(x); }
__device__ __forceinline__ float fsig(float x) { return frcp(1.0f + __expf(-x)); }
__device__ __forceinline__ float ftanh_x(float x) {
    return 1.0f - 2.0f * frcp(__expf(2.0f * x) + 1.0f);
}
__device__ __forceinline__ float fsoftplus_x(float z) {
    return fmaxf(z, 0.0f) + __logf(1.0f + __expf(-fabsf(z)));
}

// Exact reference chain at one soc value (per-block constants folded in pre1).
__device__ __forceinline__ void eval_chain(float soc,
    const float* __restrict__ w1, const float* __restrict__ pre1,
    const float* __restrict__ w2, const float* __restrict__ bb2,
    float& OCV, float& R1, float& C, float& OCVU)
{
    float h[6];
    #pragma unroll
    for (int i = 0; i < 6; ++i)
        h[i] = fsoftplus_x(fmaf(soc, w1[i], pre1[i]));
    float p0 = bb2[0], p1 = bb2[1], p2 = bb2[2], p5 = bb2[5], p6 = bb2[6];
    #pragma unroll
    for (int i = 0; i < 6; ++i) {
        p0 = fmaf(h[i], w2[7*i + 0], p0);
        p1 = fmaf(h[i], w2[7*i + 1], p1);
        p2 = fmaf(h[i], w2[7*i + 2], p2);
        p5 = fmaf(h[i], w2[7*i + 5], p5);
        p6 = fmaf(h[i], w2[7*i + 6], p6);
    }
    R1   = 0.04f * fsig(0.01f * p0);
    C    = 1e-6f * fsig(0.01f * p1);
    OCVU = fmaf(0.75f,    fsig(0.01f * p2), 0.05f);
    float ox = fmaf(0.79764f, fsig(0.01f * p5), 0.04236f);
    float oy = fmaf(0.82504f, fsig(0.01f * p6), 0.023f);
    float up = fmaf(oy, fmaf(oy, fmaf(oy, fmaf(oy, fmaf(oy, -2.2166f, 3.5146f),
                    -2.0843f), 1.6225f), -1.6518f), 4.4167f);
    up -= 4.0f * __expf(fmaf(109.451f, oy, -100.006f));
    float un = 0.063f + 0.8f * __expf(-75.0f * (ox + 0.001f));
    un = fmaf(-0.012f,  ftanh_x((ox - 0.127f) * 62.5f),        un);
    un = fmaf(-0.0118f, ftanh_x((ox - 0.155f) * 62.5f),        un);
    un = fmaf(-0.0035f, ftanh_x((ox - 0.22f)  * 50.0f),        un);
    un = fmaf(-0.0095f, ftanh_x((ox - 0.19f)  * 76.9230769f),  un);
    un = fmaf(-0.0145f, ftanh_x((ox - 0.49f)  * 50.0f),        un);
    un = fmaf(-0.08f,   ftanh_x((ox - 1.03f)  * 18.1818182f),  un);
    OCV = up - un;
}

__global__ void __launch_bounds__(BLK, 4)
voltnet_kernel(const float* __restrict__ X, const float* __restrict__ SC,
               const float* __restrict__ W1, const float* __restrict__ b1,
               const float* __restrict__ W2, const float* __restrict__ b2,
               float* __restrict__ out)
{
    __shared__ __align__(16) float ldsT[LDSN];   // t -> (later) output staging
    __shared__ __align__(16) float ldsI[LDSN];   // I
    __shared__ float  tw[NW], dw[NW], mnw[NW], mxw[NW], sA[NW], sB[NW];
    __shared__ float4 nodes[NNODE];
    __shared__ float  bcU10;

    const int b    = blockIdx.x;
    const int tid  = threadIdx.x;
    const int lane = tid & 63;
    const int wv   = tid >> 6;
    const int s    = tid * EPT;
    const int ps   = PADJ(s);          // padded start of this thread's 16 elems

    const float* __restrict__ Xrow = X + (size_t)b * TT * 3;
    const float Q  = SC[2 * b + 0];
    const float R0 = SC[2 * b + 1];

    // weights -> uniform (SGPR) loads
    float w1[18], bb1[6], w2[42], bb2[7];
    #pragma unroll
    for (int i = 0; i < 18; ++i) w1[i] = W1[i];
    #pragma unroll
    for (int i = 0; i < 6;  ++i) bb1[i] = b1[i];
    #pragma unroll
    for (int i = 0; i < 42; ++i) w2[i] = W2[i];
    #pragma unroll
    for (int i = 0; i < 7;  ++i) bb2[i] = b2[i];

    // ---- Phase 1 (WAVE-LOCAL): wave wv stages elements [1024*wv, 1024*wv+1024)
    //   groups p = 256*wv + 64*c + lane, c=0..3 (consecutive lanes ->
    //   consecutive groups: same coalescing as before).
    //   group p owns elements j0=4p..4p+3 (never straddles a pad block):
    //   q0={t0,I0,T0,t1} q1={I1,T1,t2,I2} q2={T2,t3,I3,T3}
    const float4* __restrict__ Xq = (const float4*)Xrow;
    float tsum = 0.0f;
    #pragma unroll
    for (int c = 0; c < 4; ++c) {
        int p  = (wv << 8) + (c << 6) + lane;
        float4 q0 = Xq[3 * p + 0];
        float4 q1 = Xq[3 * p + 1];
        float4 q2 = Xq[3 * p + 2];
        int jp = PADJ(4 * p);                     // mult of 4 -> 16B aligned
        vfloat4 tq = { q0.x, q0.w, q1.z, q2.y };
        vfloat4 iq = { q0.y, q1.x, q1.w, q2.z };
        *(__shared__ vfloat4*)&ldsT[jp] = tq;
        *(__shared__ vfloat4*)&ldsI[jp] = iq;
        tsum += (q0.z + q1.y) + (q2.x + q2.w);
    }
    // lane 0 needs element s-1 (previous wave's last) -> redundant global
    // load of that group's q2 (16B, L2-hit); wave 0 lane 0 is the j==0 case.
    float tprev = 0.0f, iprev = 0.0f;
    if (lane == 0 && wv > 0) {
        float4 qb = Xq[768 * wv - 1];             // q2 of group 256*wv-1
        tprev = qb.y; iprev = qb.z;               // t3, I3
    }
    // wave-local LDS producer->consumer: wait for own ds_writes, no barrier
    asm volatile("s_waitcnt lgkmcnt(0)" ::: "memory");
    if (lane > 0) { tprev = ldsT[PADJ(s - 1)]; iprev = ldsI[PADJ(s - 1)]; }

    vfloat4 tq4[4], iq4[4];
    #pragma unroll
    for (int c = 0; c < 4; ++c) {
        tq4[c] = *(const __shared__ vfloat4*)&ldsT[ps + 4 * c];
        iq4[c] = *(const __shared__ vfloat4*)&ldsI[ps + 4 * c];
    }

    // ---- Phase 2a: local SOC prefix (register chunk) ----
    float lp[EPT], Ireg[EPT];
    float run = 0.0f;
    float mnl = 1e30f, mxl = -1e30f;
    #pragma unroll
    for (int e = 0; e < EPT; ++e) {
        float tt = tq4[e >> 2][e & 3];
        float ii = iq4[e >> 2][e & 3];
        float ds = (ii + iprev) * (tt - tprev) * (1.0f / 36000.0f);
        if (s + e == 0) ds = 0.0f;
        run += ds;
        lp[e]   = run;          // inclusive local prefix (registers)
        Ireg[e] = ii;
        mnl = fminf(mnl, run);
        mxl = fmaxf(mxl, run);
        tprev = tt; iprev = ii;
    }
    float inc = run;
    #pragma unroll
    for (int d = 1; d < 64; d <<= 1) {
        float v = __shfl_up(inc, d, 64);
        if (lane >= d) inc += v;
    }
    // wave min/max of local prefix (relative to wave start)
    float mn_t = (inc - run) + mnl, mx_t = (inc - run) + mxl;
    #pragma unroll
    for (int d = 32; d > 0; d >>= 1) {
        mn_t = fminf(mn_t, __shfl_down(mn_t, d, 64));
        mx_t = fmaxf(mx_t, __shfl_down(mx_t, d, 64));
    }
    // wave Temp partial
    #pragma unroll
    for (int d = 32; d > 0; d >>= 1) tsum += __shfl_down(tsum, d, 64);
    if (lane == 0)  { tw[wv] = tsum; mnw[wv] = mn_t; mxw[wv] = mx_t; }
    if (lane == 63) dw[wv] = inc;
    __syncthreads();                                    // B1: block aggregates

    // Tmean combine: lanes<NW hold one wave aggregate, shfl tree
    float tv = (lane < NW) ? tw[lane] : 0.0f;
    #pragma unroll
    for (int d = 1; d < NW; d <<= 1) tv += __shfl_xor(tv, d, 64);
    const float Tmean = __shfl(tv, 0, 64) * (1.0f / (float)TT);

    float pre1[6];
    #pragma unroll
    for (int o = 0; o < 6; ++o)
        pre1[o] = fmaf(R0, w1[6 + o], fmaf(Tmean, w1[12 + o], bb1[o]));

    float woff = 0.0f;
    for (int w = 0; w < wv; ++w) woff += dw[w];         // wave-uniform
    const float soc_base = fmaf(Q, 0.2f, woff + (inc - run));

    // block lo/hi of soc: lanes<NW hold one wave aggregate, shfl scan+reduce.
    // Rounding delta vs serial is ulp-level, absorbed by the range pad.
    float lo, hi;
    {
        float dv  = (lane < NW) ? dw[lane]  : 0.0f;
        float mnv = (lane < NW) ? mnw[lane] : 1e30f;
        float mxv = (lane < NW) ? mxw[lane] : -1e30f;
        float pv = dv;
        #pragma unroll
        for (int d = 1; d < NW; d <<= 1) {
            float u = __shfl_up(pv, d, 64);
            if (lane >= d) pv += u;
        }
        float ex = pv - dv;                 // exclusive prefix at this lane
        float cl = ex + mnv, ch = ex + mxv;
        #pragma unroll
        for (int d = 1; d < NW; d <<= 1) {
            cl = fminf(cl, __shfl_xor(cl, d, 64));
            ch = fmaxf(ch, __shfl_xor(ch, d, 64));
        }
        lo = fmaf(Q, 0.2f, __shfl(cl, 0, 64));
        hi = fmaf(Q, 0.2f, __shfl(ch, 0, 64));
        float pad = fmaf(hi - lo, 1.0f / 256.0f, 1e-7f);
        lo -= pad; hi += pad;
    }
    const float hstep = (hi - lo) * (1.0f / (float)(NNODE - 1));
    const float invh  = (float)(NNODE - 1) * frcp(hi - lo);

    // cross-wave I[s+16] (all staging complete block-wide after B1)
    const float inext_last = (tid < BLK - 1) ? ldsI[PADJ(s + EPT)] : 0.0f;

    // ---- Node evaluation: exact reference chain at 256 soc nodes ----
    //   Stored at permuted slot NPERM(k): soc walk makes lane-to-lane dk~+-8,
    //   which collides mod-8 bank classes in a linear layout.
    if (tid < NNODE) {
        float OCV, R1v, Cv, OCVU;
        eval_chain(fmaf((float)tid, hstep, lo), w1, pre1, w2, bb2, OCV, R1v, Cv, OCVU);
        nodes[NPERM(tid)] = make_float4(OCV, R1v, Cv, 0.0f);
    }
    if (tid == 0) {
        float OCV, R1v, Cv, OCVU;
        eval_chain(Q * 0.2f, w1, pre1, w2, bb2, OCV, R1v, Cv, OCVU);  // soc(j=0)=Q/5
        bcU10 = -OCVU - Ireg[0] * R0;
    }
    __syncthreads();                                    // B2: node table

    // ---- Phase 2b: nearest-node LUT + affine coeffs; stash P->lp, Apre->Ireg ----
    float Ap = 1.0f, Bp = 0.0f;
    #pragma unroll 4
    for (int e = 0; e < EPT; ++e) {
        float soc = soc_base + lp[e];
        float ii  = Ireg[e];
        float inx = (e == EPT - 1) ? inext_last : Ireg[e + 1];

        int k = (int)fmaf(soc - lo, invh, 0.5f);
        k = (k < 0) ? 0 : ((k > NNODE - 1) ? NNODE - 1 : k);
        float4 n = nodes[NPERM(k)];

        // stash: pred[j] = P + Apre * U1_at_thread_start   (UH == 0)
        lp[e]   = fmaf(ii, R0, n.x) + Bp;
        Ireg[e] = Ap;

        float g  = (inx - ii) * n.z;
        float aj = 1.0f - g;
        float bj = g * n.y * ii;
        if (s + e == TT - 1) { aj = 1.0f; bj = 0.0f; }
        Bp = fmaf(aj, Bp, bj);
        Ap = aj * Ap;
    }

    // ---- affine block scan ((a2,b2)o(a1,b1) = (a2*a1, a2*b1+b2)) ----
    float A = Ap, B = Bp;
    #pragma unroll
    for (int d = 1; d < 64; d <<= 1) {
        float Au = __shfl_up(A, d, 64);
        float Bu = __shfl_up(B, d, 64);
        if (lane >= d) { B = fmaf(A, Bu, B); A = A * Au; }
    }
    float Aex = __shfl_up(A, 1, 64);
    float Bex = __shfl_up(B, 1, 64);
    if (lane == 0) { Aex = 1.0f; Bex = 0.0f; }
    if (lane == 63) { sA[wv] = A; sB[wv] = B; }
    __syncthreads();                                    // B3: affine aggregates
    float Ao = 1.0f, Bo = 0.0f;
    for (int w = 0; w < wv; ++w) {                      // wave-uniform
        Bo = fmaf(sA[w], Bo, sB[w]);
        Ao = sA[w] * Ao;
    }
    const float U1s = fmaf(Aex * Ao, bcU10, fmaf(Aex, Bo, Bex));

    // ---- Phase 3 (WAVE-LOCAL): combine in regs, b128 staging into own
    //   region (own wave's earlier reads of it are program-ordered), then
    //   wave-local coalesced nt stores. No barrier: store tail skews.
    #pragma unroll
    for (int c = 0; c < 4; ++c) {
        vfloat4 o;
        o.x = fmaf(Ireg[4 * c + 0], U1s, lp[4 * c + 0]);
        o.y = fmaf(Ireg[4 * c + 1], U1s, lp[4 * c + 1]);
        o.z = fmaf(Ireg[4 * c + 2], U1s, lp[4 * c + 2]);
        o.w = fmaf(Ireg[4 * c + 3], U1s, lp[4 * c + 3]);
        *(__shared__ vfloat4*)&ldsT[ps + 4 * c] = o;
    }
    asm volatile("s_waitcnt lgkmcnt(0)" ::: "memory");
    float* __restrict__ orow = out + (size_t)b * TT;
    #pragma unroll 4
    for (int c = 0; c < EPT; ++c) {
        int j = (wv << 10) + (c << 6) + lane;           // wave-local, full 64B lines
        __builtin_nontemporal_store(ldsT[PADJ(j)], &orow[j]);
    }
}

extern "C" void kernel_launch(void* const* d_in, const int* in_sizes, int n_in,
                              void* d_out, int out_size, void* d_ws, size_t ws_size,
                              hipStream_t stream)
{
    const float* X  = (const float*)d_in[0];
    const float* SC = (const float*)d_in[1];
    const float* W1 = (const float*)d_in[2];
    const float* b1 = (const float*)d_in[3];
    const float* W2 = (const float*)d_in[4];
    const float* b2 = (const float*)d_in[5];
    float* outp = (float*)d_out;
    const int B = in_sizes[1] / 2;   // SC is (B,2)
    hipLaunchKernelGGL(voltnet_kernel, dim3(B), dim3(BLK), 0, stream,
                       X, SC, W1, b1, W2, b2, outp);
}